// Round 5
// baseline (1438.281 us; speedup 1.0000x reference)
//
#include <hip/hip_runtime.h>
#include <cstdint>
#include <cstddef>
#include <type_traits>

#define N_NODES 20000
#define N_EDGES 320000
#define T_STEPS 12
#define HEADS   4
#define NEG_SLOPE 0.2f

typedef unsigned short u16;
typedef unsigned int   u32;

using bf16x8 = __attribute__((ext_vector_type(8))) __bf16;
using f32x4v = __attribute__((ext_vector_type(4))) float;

__device__ __forceinline__ u16 bf16_rne(float f) {
    u32 u = __float_as_uint(f);
    u += 0x7fffu + ((u >> 16) & 1u);
    return (u16)(u >> 16);
}

// ---------------- CSR build (dst-sorted), once per call ----------------

__global__ void hist_kernel(const int* __restrict__ dst, int* __restrict__ cnt) {
    int e = blockIdx.x * 256 + threadIdx.x;
    if (e < N_EDGES) atomicAdd(&cnt[dst[e]], 1);
}

__global__ __launch_bounds__(1024) void scan_kernel(const int* __restrict__ cnt,
                                                    int* __restrict__ rp) {
    __shared__ int sd[1024];
    __shared__ int sbase;
    int tid = threadIdx.x;
    if (tid == 0) sbase = 0;
    __syncthreads();
    for (int chunk = 0; chunk < N_NODES; chunk += 1024) {
        int i = chunk + tid;
        int v = (i < N_NODES) ? cnt[i] : 0;
        sd[tid] = v;
        __syncthreads();
        #pragma unroll
        for (int off = 1; off < 1024; off <<= 1) {
            int t = (tid >= off) ? sd[tid - off] : 0;
            __syncthreads();
            sd[tid] += t;
            __syncthreads();
        }
        int incl = sd[tid];
        int base = sbase;
        if (i < N_NODES) rp[i] = base + incl - v;   // exclusive prefix
        __syncthreads();
        if (tid == 1023) sbase = base + incl;
        __syncthreads();
    }
    if (tid == 0) rp[N_NODES] = sbase;              // == N_EDGES
}

__global__ void scatter_kernel(const int* __restrict__ src, const int* __restrict__ dst,
                               const int* __restrict__ rp, int* __restrict__ tmp,
                               int* __restrict__ col) {
    int e = blockIdx.x * 256 + threadIdx.x;
    if (e < N_EDGES) {
        int d = dst[e];
        int pos = rp[d] + atomicAdd(&tmp[d], 1);
        col[pos] = src[e];
    }
}

// ---------------- split-bf16 helpers ----------------
// fp32 f -> bf16 hi (RNE) + bf16 lo (RNE of residual). hi+lo carries ~16
// mantissa bits: rel err ~2^-16, so 3-product MFMA (hh+hl+lh) ~ fp32 GEMM.

#define SPLIT2(fx, fy, H, L) do {                                          \
    u32 u0_ = __float_as_uint(fx), u1_ = __float_as_uint(fy);              \
    u32 r0_ = u0_ + 0x7fffu + ((u0_ >> 16) & 1u);                          \
    u32 r1_ = u1_ + 0x7fffu + ((u1_ >> 16) & 1u);                          \
    (H) = (r1_ & 0xffff0000u) | (r0_ >> 16);                               \
    float e0_ = (fx) - __uint_as_float(r0_ & 0xffff0000u);                 \
    float e1_ = (fy) - __uint_as_float(r1_ & 0xffff0000u);                 \
    u32 v0_ = __float_as_uint(e0_), v1_ = __float_as_uint(e1_);            \
    v0_ += 0x7fffu + ((v0_ >> 16) & 1u);                                   \
    v1_ += 0x7fffu + ((v1_ >> 16) & 1u);                                   \
    (L) = (v1_ & 0xffff0000u) | (v0_ >> 16);                               \
} while (0)

// W [K][N] fp32 -> Wt_hi/Wt_lo [N][K] bf16 (transposed so the GEMM B-tile
// staging is a contiguous K-major read). Tiny (<=64K elems), runs once.
__global__ void wsplit_kernel(const float* __restrict__ W, u16* __restrict__ Wh,
                              u16* __restrict__ Wl, int K, int N) {
    int idx = blockIdx.x * 256 + threadIdx.x;
    if (idx >= K * N) return;
    int k = idx / N, n = idx - k * N;
    float f = W[idx];
    u32 u = __float_as_uint(f);
    u32 r = u + 0x7fffu + ((u >> 16) & 1u);
    u16 hb = (u16)(r >> 16);
    float lf = f - __uint_as_float(r & 0xffff0000u);
    u32 v = __float_as_uint(lf);
    v = v + 0x7fffu + ((v >> 16) & 1u);
    Wh[(size_t)n * K + k] = hb;
    Wl[(size_t)n * K + k] = (u16)(v >> 16);
}

// ---------------- MFMA GEMM (layer 1): A fp32, in-kernel split ----------

template <typename AT>
__global__ __launch_bounds__(256) void gemm_mfma(
        const AT* __restrict__ A, const u16* __restrict__ Bh,
        const u16* __restrict__ Bl, _Float16* __restrict__ Y,
        int Mrows, int Ncols, int K, int strideT, int tbase, int nT) {
    constexpr bool A_F32 = std::is_same<AT, float>::value;
    __shared__ u16 As_h[128][40];   // pad 32->40: 80B rows, 16B aligned
    __shared__ u16 As_l[128][40];
    __shared__ u16 Bs_h[128][40];
    __shared__ u16 Bs_l[128][40];

    int tid  = threadIdx.x;
    int wave = tid >> 6, lane = tid & 63;
    int wr = wave >> 1, wc = wave & 1;
    int fr = lane & 15, fg = lane >> 4;
    int row0 = blockIdx.x * 128;
    int col0 = blockIdx.y * 128;

    int am = tid >> 1;
    int ak = (tid & 1) << 4;
    const AT* ap = nullptr;
    {
        int r = row0 + am;
        if (r < Mrows) {
            int n = r / nT, tl = r - n * nT;
            ap = A + ((size_t)n * strideT + (size_t)(tbase + tl)) * (size_t)K + ak;
        }
    }
    int bn = tid >> 1;
    int bk = (tid & 1) << 4;
    const u16* bph = Bh + (size_t)(col0 + bn) * K + bk;
    const u16* bpl = Bl + (size_t)(col0 + bn) * K + bk;

    f32x4v acc[4][4] = {};

    float4 fa4[4];
    uint4  ra[2];
    uint4 vbh0, vbh1, vbl0, vbl1;

#define LOAD_TILE(K0) do {                                                  \
    if (ap) {                                                               \
        if (A_F32) {                                                        \
            const float* p_ = (const float*)ap + (K0);                      \
            fa4[0] = *(const float4*)(p_);      fa4[1] = *(const float4*)(p_ + 4);  \
            fa4[2] = *(const float4*)(p_ + 8);  fa4[3] = *(const float4*)(p_ + 12); \
        } else {                                                            \
            const _Float16* p_ = (const _Float16*)ap + (K0);                \
            ra[0] = *(const uint4*)(p_);  ra[1] = *(const uint4*)(p_ + 8);  \
        }                                                                   \
    } else {                                                                \
        fa4[0] = fa4[1] = fa4[2] = fa4[3] = make_float4(0.f, 0.f, 0.f, 0.f);\
        ra[0] = ra[1] = make_uint4(0, 0, 0, 0);                             \
    }                                                                       \
    vbh0 = *(const uint4*)(bph + (K0));  vbh1 = *(const uint4*)(bph + (K0) + 8); \
    vbl0 = *(const uint4*)(bpl + (K0));  vbl1 = *(const uint4*)(bpl + (K0) + 8); \
} while (0)

    LOAD_TILE(0);

    for (int k0 = 0; k0 < K; k0 += 32) {
        float fv[16];
        if (A_F32) {
            fv[0]=fa4[0].x; fv[1]=fa4[0].y; fv[2]=fa4[0].z; fv[3]=fa4[0].w;
            fv[4]=fa4[1].x; fv[5]=fa4[1].y; fv[6]=fa4[1].z; fv[7]=fa4[1].w;
            fv[8]=fa4[2].x; fv[9]=fa4[2].y; fv[10]=fa4[2].z; fv[11]=fa4[2].w;
            fv[12]=fa4[3].x; fv[13]=fa4[3].y; fv[14]=fa4[3].z; fv[15]=fa4[3].w;
        } else {
            const _Float16* hx = (const _Float16*)ra;
            #pragma unroll
            for (int i = 0; i < 16; ++i) fv[i] = (float)hx[i];
        }
        u32 h0, h1, h2, h3, h4, h5, h6, h7;
        u32 l0, l1, l2, l3, l4, l5, l6, l7;
        SPLIT2(fv[0],  fv[1],  h0, l0); SPLIT2(fv[2],  fv[3],  h1, l1);
        SPLIT2(fv[4],  fv[5],  h2, l2); SPLIT2(fv[6],  fv[7],  h3, l3);
        SPLIT2(fv[8],  fv[9],  h4, l4); SPLIT2(fv[10], fv[11], h5, l5);
        SPLIT2(fv[12], fv[13], h6, l6); SPLIT2(fv[14], fv[15], h7, l7);
        *(uint4*)&As_h[am][ak]     = make_uint4(h0, h1, h2, h3);
        *(uint4*)&As_h[am][ak + 8] = make_uint4(h4, h5, h6, h7);
        *(uint4*)&As_l[am][ak]     = make_uint4(l0, l1, l2, l3);
        *(uint4*)&As_l[am][ak + 8] = make_uint4(l4, l5, l6, l7);
        *(uint4*)&Bs_h[bn][bk]     = vbh0;
        *(uint4*)&Bs_h[bn][bk + 8] = vbh1;
        *(uint4*)&Bs_l[bn][bk]     = vbl0;
        *(uint4*)&Bs_l[bn][bk + 8] = vbl1;
        __syncthreads();

        if (k0 + 32 < K) LOAD_TILE(k0 + 32);

        bf16x8 fah[4], fal[4], fbh[4], fbl[4];
        #pragma unroll
        for (int i = 0; i < 4; ++i) {
            fah[i] = *(const bf16x8*)&As_h[wr * 64 + i * 16 + fr][fg * 8];
            fal[i] = *(const bf16x8*)&As_l[wr * 64 + i * 16 + fr][fg * 8];
        }
        #pragma unroll
        for (int j = 0; j < 4; ++j) {
            fbh[j] = *(const bf16x8*)&Bs_h[wc * 64 + j * 16 + fr][fg * 8];
            fbl[j] = *(const bf16x8*)&Bs_l[wc * 64 + j * 16 + fr][fg * 8];
        }
        #pragma unroll
        for (int i = 0; i < 4; ++i)
            #pragma unroll
            for (int j = 0; j < 4; ++j) {
                acc[i][j] = __builtin_amdgcn_mfma_f32_16x16x32_bf16(fah[i], fbh[j], acc[i][j], 0, 0, 0);
                acc[i][j] = __builtin_amdgcn_mfma_f32_16x16x32_bf16(fah[i], fbl[j], acc[i][j], 0, 0, 0);
                acc[i][j] = __builtin_amdgcn_mfma_f32_16x16x32_bf16(fal[i], fbh[j], acc[i][j], 0, 0, 0);
            }
        __syncthreads();
    }
#undef LOAD_TILE

    #pragma unroll
    for (int i = 0; i < 4; ++i) {
        #pragma unroll
        for (int q = 0; q < 4; ++q) {
            int rr = row0 + wr * 64 + i * 16 + fg * 4 + q;
            if (rr < Mrows) {
                _Float16* yp = Y + (size_t)rr * Ncols + col0 + wc * 64 + fr;
                #pragma unroll
                for (int j = 0; j < 4; ++j) yp[j * 16] = (_Float16)acc[i][j][q];
            }
        }
    }
}

// ---------------- MFMA GEMM (layers 2/3): pre-split bf16 A, fused alpha ----
// A given as bf16 hi/lo [node][t][K]; staging = pure uint4 copies.
// Epilogue computes alpha_s/alpha_d per (row, head): each (row,head) has
// exactly ONE producer (block-col, wave-wc, fr-group) -> plain stores,
// no atomics, no memset. CC = head channel width of the OUTPUT (64 or 32).

template <int CC>
__global__ __launch_bounds__(256) void gemm_pair(
        const u16* __restrict__ Ah, const u16* __restrict__ Al,
        const u16* __restrict__ Bh, const u16* __restrict__ Bl,
        _Float16* __restrict__ Y,
        const float* __restrict__ a_src, const float* __restrict__ a_dst,
        float* __restrict__ as_out, float* __restrict__ ad_out,
        int Mrows, int Ncols, int K, int strideT, int tbase, int nT) {
    __shared__ u16 As_h[128][40];
    __shared__ u16 As_l[128][40];
    __shared__ u16 Bs_h[128][40];
    __shared__ u16 Bs_l[128][40];

    int tid  = threadIdx.x;
    int wave = tid >> 6, lane = tid & 63;
    int wr = wave >> 1, wc = wave & 1;
    int fr = lane & 15, fg = lane >> 4;
    int row0 = blockIdx.x * 128;
    int col0 = blockIdx.y * 128;

    int am = tid >> 1;
    int ak = (tid & 1) << 4;
    size_t aoff = 0;
    bool avalid = false;
    {
        int r = row0 + am;
        if (r < Mrows) {
            int n = r / nT, tl = r - n * nT;
            aoff = ((size_t)n * strideT + (size_t)(tbase + tl)) * (size_t)K + ak;
            avalid = true;
        }
    }
    int bn = tid >> 1;
    int bk = (tid & 1) << 4;
    const u16* bph = Bh + (size_t)(col0 + bn) * K + bk;
    const u16* bpl = Bl + (size_t)(col0 + bn) * K + bk;

    f32x4v acc[4][4] = {};
    uint4 rah0, rah1, ral0, ral1, rbh0, rbh1, rbl0, rbl1;

#define LOAD_TILE(K0) do {                                                       \
    if (avalid) {                                                                \
        rah0 = *(const uint4*)(Ah + aoff + (K0));                                \
        rah1 = *(const uint4*)(Ah + aoff + (K0) + 8);                            \
        ral0 = *(const uint4*)(Al + aoff + (K0));                                \
        ral1 = *(const uint4*)(Al + aoff + (K0) + 8);                            \
    } else {                                                                     \
        rah0 = rah1 = ral0 = ral1 = make_uint4(0, 0, 0, 0);                      \
    }                                                                            \
    rbh0 = *(const uint4*)(bph + (K0));  rbh1 = *(const uint4*)(bph + (K0) + 8); \
    rbl0 = *(const uint4*)(bpl + (K0));  rbl1 = *(const uint4*)(bpl + (K0) + 8); \
} while (0)

    LOAD_TILE(0);

    for (int k0 = 0; k0 < K; k0 += 32) {
        *(uint4*)&As_h[am][ak]     = rah0;
        *(uint4*)&As_h[am][ak + 8] = rah1;
        *(uint4*)&As_l[am][ak]     = ral0;
        *(uint4*)&As_l[am][ak + 8] = ral1;
        *(uint4*)&Bs_h[bn][bk]     = rbh0;
        *(uint4*)&Bs_h[bn][bk + 8] = rbh1;
        *(uint4*)&Bs_l[bn][bk]     = rbl0;
        *(uint4*)&Bs_l[bn][bk + 8] = rbl1;
        __syncthreads();

        if (k0 + 32 < K) LOAD_TILE(k0 + 32);

        bf16x8 fah[4], fal[4], fbh[4], fbl[4];
        #pragma unroll
        for (int i = 0; i < 4; ++i) {
            fah[i] = *(const bf16x8*)&As_h[wr * 64 + i * 16 + fr][fg * 8];
            fal[i] = *(const bf16x8*)&As_l[wr * 64 + i * 16 + fr][fg * 8];
        }
        #pragma unroll
        for (int j = 0; j < 4; ++j) {
            fbh[j] = *(const bf16x8*)&Bs_h[wc * 64 + j * 16 + fr][fg * 8];
            fbl[j] = *(const bf16x8*)&Bs_l[wc * 64 + j * 16 + fr][fg * 8];
        }
        #pragma unroll
        for (int i = 0; i < 4; ++i)
            #pragma unroll
            for (int j = 0; j < 4; ++j) {
                acc[i][j] = __builtin_amdgcn_mfma_f32_16x16x32_bf16(fah[i], fbh[j], acc[i][j], 0, 0, 0);
                acc[i][j] = __builtin_amdgcn_mfma_f32_16x16x32_bf16(fah[i], fbl[j], acc[i][j], 0, 0, 0);
                acc[i][j] = __builtin_amdgcn_mfma_f32_16x16x32_bf16(fal[i], fbh[j], acc[i][j], 0, 0, 0);
            }
        __syncthreads();
    }
#undef LOAD_TILE

    // ---- epilogue: Y store + fused alpha ----
    constexpr int HPB = 64 / CC;   // heads per 64-col wave half
    constexpr int JH  = 4 / HPB;   // j-frags per head
    int headbase = (col0 + wc * 64) / CC;
    float wvs[4], wvd[4];
    #pragma unroll
    for (int j = 0; j < 4; ++j) {
        int c  = (j * 16 + fr) % CC;
        int hd = headbase + j / JH;
        wvs[j] = a_src[hd * CC + c];
        wvd[j] = a_dst[hd * CC + c];
    }
    #pragma unroll
    for (int i = 0; i < 4; ++i) {
        #pragma unroll
        for (int q = 0; q < 4; ++q) {
            int rr = row0 + wr * 64 + i * 16 + fg * 4 + q;
            if (rr < Mrows) {
                _Float16* yp = Y + (size_t)rr * Ncols + col0 + wc * 64 + fr;
                #pragma unroll
                for (int j = 0; j < 4; ++j) yp[j * 16] = (_Float16)acc[i][j][q];
                #pragma unroll
                for (int hh = 0; hh < HPB; ++hh) {
                    float sa = 0.f, sd = 0.f;
                    #pragma unroll
                    for (int jj = 0; jj < JH; ++jj) {
                        int j = hh * JH + jj;
                        sa = fmaf(acc[i][j][q], wvs[j], sa);
                        sd = fmaf(acc[i][j][q], wvd[j], sd);
                    }
                    #pragma unroll
                    for (int off = 1; off < 16; off <<= 1) {
                        sa += __shfl_xor(sa, off);
                        sd += __shfl_xor(sd, off);
                    }
                    if (fr == 0) {
                        as_out[(size_t)rr * HEADS + headbase + hh] = sa;
                        ad_out[(size_t)rr * HEADS + headbase + hh] = sd;
                    }
                }
            }
        }
    }
}

// ---------------- per-row attention logits (layer 1 only) ----------------

template <int C>
__global__ __launch_bounds__(256) void alpha_kernel(
        const _Float16* __restrict__ h, const float* __restrict__ a_src,
        const float* __restrict__ a_dst, float* __restrict__ as,
        float* __restrict__ ad, int Mrows) {
    constexpr int HC = HEADS * C;
    constexpr int V  = HC / 64;
    int r = blockIdx.x * 4 + (threadIdx.x >> 6);
    if (r >= Mrows) return;
    int lane = threadIdx.x & 63;
    int ch0 = lane * V;
    int head = lane >> 4;
    const _Float16* hp = h + (size_t)r * HC + ch0;
    float s = 0.f, d = 0.f;
    #pragma unroll
    for (int i = 0; i < V; ++i) {
        float v = (float)hp[i];
        s = fmaf(v, a_src[ch0 + i], s);
        d = fmaf(v, a_dst[ch0 + i], d);
    }
    #pragma unroll
    for (int off = 1; off < 16; off <<= 1) {
        s += __shfl_xor(s, off);
        d += __shfl_xor(d, off);
    }
    if ((lane & 15) == 0) {
        as[(size_t)r * HEADS + head] = s;
        ad[(size_t)r * HEADS + head] = d;
    }
}

// ---------------- fused softmax + aggregation ----------------
// No max-pass: exp(v) with v clamped at 80 is mathematically identical to
// exp(v - max) after the normalization. grid (N_NODES, NTOT/NT).
// SPLIT=true: output written as bf16 hi/lo pair (next layer's GEMM A).

template <int NTOT, int NT, int C, bool RELU, bool TO_OUT, bool SPLIT>
__global__ __launch_bounds__(HEADS * C) void agg_kernel(
        const _Float16* __restrict__ h, const float* __restrict__ as,
        const float* __restrict__ ad, const int* __restrict__ rp,
        const int* __restrict__ col, const float* __restrict__ bias,
        float* __restrict__ out, u16* __restrict__ outh,
        u16* __restrict__ outl, int t0) {
    constexpr int HC  = HEADS * C;
    constexpr int NW  = HC / 64;       // waves per block (4 or 2)
    constexpr int HPW = HEADS / NW;    // heads per wave in phase A
    constexpr int CHUNK = 64;
    constexpr int WSTR = NT * HEADS + 1;   // odd -> max 2-way bank alias
    constexpr int CG  = HC / 8;        // channel groups
    constexpr int EP  = HC / CG;       // edge-parallel factor = 8

    __shared__ int   s_col[CHUNK];
    __shared__ float s_w[CHUNK][WSTR];
    __shared__ float s_red[NW][NT][HC];
    __shared__ float s_inv[NT][HEADS];

    int n = blockIdx.x;
    int tbase = blockIdx.y * NT;
    int tid = threadIdx.x;
    int wave = tid >> 6, lane = tid & 63;

    int beg = rp[n], end = rp[n + 1];

    float dsum[HPW][NT], adv[HPW][NT];
    #pragma unroll
    for (int hp = 0; hp < HPW; ++hp) {
        int head = wave + hp * NW;
        #pragma unroll
        for (int t = 0; t < NT; ++t) {
            dsum[hp][t] = 0.f;
            adv[hp][t] = ad[((size_t)n * NTOT + tbase + t) * HEADS + head];
        }
    }

    int cg = tid & (CG - 1);
    int eg = tid / CG;
    int hcg = (cg * 8) / C;            // head of this channel group
    float acc[NT][8];
    #pragma unroll
    for (int t = 0; t < NT; ++t)
        #pragma unroll
        for (int j = 0; j < 8; ++j) acc[t][j] = 0.f;

    for (int c0 = beg; c0 < end; c0 += CHUNK) {
        int cnt = min(CHUNK, end - c0);
        if (tid < cnt) s_col[tid] = col[c0 + tid];
        __syncthreads();
        if (lane < cnt) {
            int s = s_col[lane];
            #pragma unroll
            for (int hp = 0; hp < HPW; ++hp) {
                int head = wave + hp * NW;
                #pragma unroll
                for (int t = 0; t < NT; ++t) {
                    float v = as[((size_t)s * NTOT + tbase + t) * HEADS + head] + adv[hp][t];
                    v = v > 0.f ? v : NEG_SLOPE * v;
                    v = fminf(v, 80.f);             // overflow guard
                    float w = __expf(v);
                    dsum[hp][t] += w;
                    s_w[lane][t * HEADS + head] = w;
                }
            }
        }
        __syncthreads();
        for (int e = eg; e < cnt; e += EP) {
            int s = s_col[e];
            const _Float16* hb = h + ((size_t)s * NTOT + tbase) * HC + cg * 8;
            #pragma unroll
            for (int t = 0; t < NT; ++t) {
                float w = s_w[e][t * HEADS + hcg];
                uint4 hv = *(const uint4*)(hb + (size_t)t * HC);
                const _Float16* hx = (const _Float16*)&hv;
                #pragma unroll
                for (int j = 0; j < 8; ++j)
                    acc[t][j] = fmaf((float)hx[j], w, acc[t][j]);
            }
        }
        __syncthreads();
    }

    #pragma unroll
    for (int off = 32; off; off >>= 1)
        #pragma unroll
        for (int hp = 0; hp < HPW; ++hp)
            #pragma unroll
            for (int t = 0; t < NT; ++t)
                dsum[hp][t] += __shfl_xor(dsum[hp][t], off);
    if (lane == 0) {
        #pragma unroll
        for (int hp = 0; hp < HPW; ++hp)
            #pragma unroll
            for (int t = 0; t < NT; ++t)
                s_inv[t][wave + hp * NW] = 1.f / (dsum[hp][t] + 1e-16f);
    }

    #pragma unroll
    for (int off = CG; off < 64; off <<= 1)
        #pragma unroll
        for (int t = 0; t < NT; ++t)
            #pragma unroll
            for (int j = 0; j < 8; ++j)
                acc[t][j] += __shfl_xor(acc[t][j], off);
    if (lane < CG) {
        #pragma unroll
        for (int t = 0; t < NT; ++t) {
            *(float4*)&s_red[wave][t][lane * 8] =
                make_float4(acc[t][0], acc[t][1], acc[t][2], acc[t][3]);
            *(float4*)&s_red[wave][t][lane * 8 + 4] =
                make_float4(acc[t][4], acc[t][5], acc[t][6], acc[t][7]);
        }
    }
    __syncthreads();

    int head_b = tid / C;
    float bv = bias[tid];
    #pragma unroll
    for (int t = 0; t < NT; ++t) {
        float o = 0.f;
        #pragma unroll
        for (int w = 0; w < NW; ++w) o += s_red[w][t][tid];
        o = o * s_inv[t][head_b] + bv;
        if (RELU) o = fmaxf(o, 0.f);
        if (TO_OUT) {
            out[((size_t)n * T_STEPS + (size_t)(t0 + tbase + t)) * HC + tid] = o;
        } else if (SPLIT) {
            u16 hb16 = bf16_rne(o);
            float lf = o - __uint_as_float(((u32)hb16) << 16);
            size_t idx = ((size_t)n * NTOT + tbase + t) * HC + tid;
            outh[idx] = hb16;
            outl[idx] = bf16_rne(lf);
        }
    }
}

// ---------------- host ----------------

static inline size_t align256(size_t x) { return (x + 255) & ~(size_t)255; }

static size_t need_ws(int tc) {
    size_t s = 0;
    s += align256(sizeof(int) * (N_NODES + 1));
    s += align256(sizeof(int) * N_NODES);
    s += align256(sizeof(int) * N_EDGES);
    s += 2 * align256(2ull * 128 * 256);                   // w1 hi/lo
    s += 2 * align256(2ull * 256 * 256);                   // w2 hi/lo
    s += 2 * align256(2ull * 256 * 128);                   // w3 hi/lo
    s += 2 * align256(4ull * tc * N_NODES * HEADS);        // as, ad
    s += align256(2ull * tc * N_NODES * 256);              // hbuf (fp16)
    s += 2 * align256(2ull * tc * N_NODES * 256);          // bufh, bufl (bf16)
    return s;
}

struct Ptrs {
    const float *x, *W1, *av1, *aw1, *b1, *W2, *av2, *aw2, *b2, *W3, *av3, *aw3, *b3;
    float* out;
    int *rp, *col;
    u16 *w1h, *w1l, *w2h, *w2l, *w3h, *w3l;
    float *as_b, *ad_b;
    _Float16 *hbuf;
    u16 *bufh, *bufl;
};

template <int NTOT>
static void run_chunk(const Ptrs& P, int t0, hipStream_t stream) {
    constexpr int NTA  = (NTOT % 3 == 0 && NTOT > 3) ? 3 : NTOT;
    constexpr int NSPL = NTOT / NTA;
    int Mrows = NTOT * N_NODES;
    dim3 gg1((Mrows + 127) / 128, 2);   // N=256
    dim3 gg3((Mrows + 127) / 128, 1);   // N=128
    dim3 ga(N_NODES, NSPL);
    int ablocks = (Mrows + 3) / 4;

    // layer 1: x -> h (K=128, out 256); alpha standalone
    gemm_mfma<float><<<gg1, 256, 0, stream>>>(P.x, P.w1h, P.w1l, P.hbuf, Mrows, 256, 128, T_STEPS, t0, NTOT);
    alpha_kernel<64><<<ablocks, 256, 0, stream>>>(P.hbuf, P.av1, P.aw1, P.as_b, P.ad_b, Mrows);
    agg_kernel<NTOT, NTA, 64, true, false, true><<<ga, 256, 0, stream>>>(
        P.hbuf, P.as_b, P.ad_b, P.rp, P.col, P.b1, nullptr, P.bufh, P.bufl, t0);

    // layer 2: buf(split) -> h (K=256, out 256); alpha fused into epilogue
    gemm_pair<64><<<gg1, 256, 0, stream>>>(P.bufh, P.bufl, P.w2h, P.w2l, P.hbuf,
                                           P.av2, P.aw2, P.as_b, P.ad_b,
                                           Mrows, 256, 256, NTOT, 0, NTOT);
    agg_kernel<NTOT, NTA, 64, true, false, true><<<ga, 256, 0, stream>>>(
        P.hbuf, P.as_b, P.ad_b, P.rp, P.col, P.b2, nullptr, P.bufh, P.bufl, t0);

    // layer 3: buf(split) -> h (K=256, out 128) -> d_out; alpha fused
    gemm_pair<32><<<gg3, 256, 0, stream>>>(P.bufh, P.bufl, P.w3h, P.w3l, P.hbuf,
                                           P.av3, P.aw3, P.as_b, P.ad_b,
                                           Mrows, 128, 256, NTOT, 0, NTOT);
    agg_kernel<NTOT, NTA, 32, false, true, false><<<ga, 128, 0, stream>>>(
        P.hbuf, P.as_b, P.ad_b, P.rp, P.col, P.b3, P.out, nullptr, nullptr, t0);
}

extern "C" void kernel_launch(void* const* d_in, const int* in_sizes, int n_in,
                              void* d_out, int out_size, void* d_ws, size_t ws_size,
                              hipStream_t stream) {
    Ptrs P;
    P.x   = (const float*)d_in[0];
    const int* eidx = (const int*)d_in[1];
    P.W1 = (const float*)d_in[2];  P.av1 = (const float*)d_in[3];
    P.aw1 = (const float*)d_in[4]; P.b1 = (const float*)d_in[5];
    P.W2 = (const float*)d_in[6];  P.av2 = (const float*)d_in[7];
    P.aw2 = (const float*)d_in[8]; P.b2 = (const float*)d_in[9];
    P.W3 = (const float*)d_in[10]; P.av3 = (const float*)d_in[11];
    P.aw3 = (const float*)d_in[12]; P.b3 = (const float*)d_in[13];
    P.out = (float*)d_out;

    const int* src = eidx;
    const int* dst = eidx + N_EDGES;

    int Tc = 1;
    const int cands[6] = {12, 6, 4, 3, 2, 1};
    for (int k = 0; k < 6; ++k) {
        if (need_ws(cands[k]) <= ws_size) { Tc = cands[k]; break; }
    }

    char* p = (char*)d_ws;
    P.rp  = (int*)p; p += align256(sizeof(int) * (N_NODES + 1));
    int* cnt = (int*)p; p += align256(sizeof(int) * N_NODES);
    P.col = (int*)p; p += align256(sizeof(int) * N_EDGES);
    P.w1h = (u16*)p; p += align256(2ull * 128 * 256);
    P.w1l = (u16*)p; p += align256(2ull * 128 * 256);
    P.w2h = (u16*)p; p += align256(2ull * 256 * 256);
    P.w2l = (u16*)p; p += align256(2ull * 256 * 256);
    P.w3h = (u16*)p; p += align256(2ull * 256 * 128);
    P.w3l = (u16*)p; p += align256(2ull * 256 * 128);
    P.as_b = (float*)p; p += align256(4ull * Tc * N_NODES * HEADS);
    P.ad_b = (float*)p; p += align256(4ull * Tc * N_NODES * HEADS);
    P.hbuf = (_Float16*)p; p += align256(2ull * Tc * N_NODES * 256);
    P.bufh = (u16*)p; p += align256(2ull * Tc * N_NODES * 256);
    P.bufl = (u16*)p;

    // --- build CSR ---
    hipMemsetAsync(cnt, 0, sizeof(int) * N_NODES, stream);
    hist_kernel<<<(N_EDGES + 255) / 256, 256, 0, stream>>>(dst, cnt);
    scan_kernel<<<1, 1024, 0, stream>>>(cnt, P.rp);
    hipMemsetAsync(cnt, 0, sizeof(int) * N_NODES, stream);
    scatter_kernel<<<(N_EDGES + 255) / 256, 256, 0, stream>>>(src, dst, P.rp, cnt, P.col);

    // --- split/transpose weights to bf16 hi/lo (once) ---
    wsplit_kernel<<<(128 * 256 + 255) / 256, 256, 0, stream>>>(P.W1, P.w1h, P.w1l, 128, 256);
    wsplit_kernel<<<(256 * 256 + 255) / 256, 256, 0, stream>>>(P.W2, P.w2h, P.w2l, 256, 256);
    wsplit_kernel<<<(256 * 128 + 255) / 256, 256, 0, stream>>>(P.W3, P.w3h, P.w3l, 256, 128);

    for (int t0 = 0; t0 < T_STEPS; t0 += Tc) {
        switch (Tc) {
            case 12: run_chunk<12>(P, t0, stream); break;
            case 6:  run_chunk<6>(P, t0, stream); break;
            case 4:  run_chunk<4>(P, t0, stream); break;
            case 3:  run_chunk<3>(P, t0, stream); break;
            case 2:  run_chunk<2>(P, t0, stream); break;
            default: run_chunk<1>(P, t0, stream); break;
        }
    }
}

// Round 6
// 1417.405 us; speedup vs baseline: 1.0147x; 1.0147x over previous
//
#include <hip/hip_runtime.h>
#include <cstdint>
#include <cstddef>
#include <type_traits>

#define N_NODES 20000
#define N_EDGES 320000
#define T_STEPS 12
#define HEADS   4
#define NEG_SLOPE 0.2f

typedef unsigned short u16;
typedef unsigned int   u32;

using f16x8  = __attribute__((ext_vector_type(8))) _Float16;
using f32x4v = __attribute__((ext_vector_type(4))) float;

// ---------------- CSR build (dst-sorted), once per call ----------------

__global__ void hist_kernel(const int* __restrict__ dst, int* __restrict__ cnt) {
    int e = blockIdx.x * 256 + threadIdx.x;
    if (e < N_EDGES) atomicAdd(&cnt[dst[e]], 1);
}

__global__ __launch_bounds__(1024) void scan_kernel(const int* __restrict__ cnt,
                                                    int* __restrict__ rp) {
    __shared__ int sd[1024];
    __shared__ int sbase;
    int tid = threadIdx.x;
    if (tid == 0) sbase = 0;
    __syncthreads();
    for (int chunk = 0; chunk < N_NODES; chunk += 1024) {
        int i = chunk + tid;
        int v = (i < N_NODES) ? cnt[i] : 0;
        sd[tid] = v;
        __syncthreads();
        #pragma unroll
        for (int off = 1; off < 1024; off <<= 1) {
            int t = (tid >= off) ? sd[tid - off] : 0;
            __syncthreads();
            sd[tid] += t;
            __syncthreads();
        }
        int incl = sd[tid];
        int base = sbase;
        if (i < N_NODES) rp[i] = base + incl - v;   // exclusive prefix
        __syncthreads();
        if (tid == 1023) sbase = base + incl;
        __syncthreads();
    }
    if (tid == 0) rp[N_NODES] = sbase;              // == N_EDGES
}

__global__ void scatter_kernel(const int* __restrict__ src, const int* __restrict__ dst,
                               const int* __restrict__ rp, int* __restrict__ tmp,
                               int* __restrict__ col) {
    int e = blockIdx.x * 256 + threadIdx.x;
    if (e < N_EDGES) {
        int d = dst[e];
        int pos = rp[d] + atomicAdd(&tmp[d], 1);
        col[pos] = src[e];
    }
}

// ---------------- split-fp16 weight prep ----------------
// W [K][N] fp32 -> Wt_hi [N][K] fp16 (RNE) + Wt_lo [N][K] fp16 = residual*2048.
// hi+lo carries ~22 mantissa bits (~fp32); scale keeps lo in fp16 normal range.
// GEMM computes acc1 = A*W_hi, acc2 = A*W_lo; out = acc1 + acc2/2048.

__global__ void wsplit_kernel(const float* __restrict__ W, _Float16* __restrict__ Wh,
                              _Float16* __restrict__ Wl, int K, int N) {
    int idx = blockIdx.x * 256 + threadIdx.x;
    if (idx >= K * N) return;
    int k = idx / N, n = idx - k * N;
    float f = W[idx];
    _Float16 hf = (_Float16)f;                  // RNE
    float lf = (f - (float)hf) * 2048.0f;
    Wh[(size_t)n * K + k] = hf;
    Wl[(size_t)n * K + k] = (_Float16)lf;
}

// ---------------- MFMA GEMM: Y = A @ W, split-fp16 W, 128x128 tile ----------
// A fp32 (layer 1: converted to fp16 in staging) or fp16 (layers 2/3: pure
// copy staging, zero conversion VALU). 2 f16 MFMA per (i,j) per K-step.
// C/D layout (verified, dtype-independent): col = lane&15, row = (lane>>4)*4+reg.

template <typename AT>
__global__ __launch_bounds__(256) void gemm_mfma(
        const AT* __restrict__ A, const _Float16* __restrict__ Bh,
        const _Float16* __restrict__ Bl, _Float16* __restrict__ Y,
        int Mrows, int Ncols, int K, int strideT, int tbase, int nT) {
    constexpr bool A_F32 = std::is_same<AT, float>::value;
    __shared__ _Float16 As[128][40];    // pad 32->40: 2-way bank alias max
    __shared__ _Float16 Bs_h[128][40];
    __shared__ _Float16 Bs_l[128][40];

    int tid  = threadIdx.x;
    int wave = tid >> 6, lane = tid & 63;
    int wr = wave >> 1, wc = wave & 1;
    int fr = lane & 15, fg = lane >> 4;
    int row0 = blockIdx.x * 128;
    int col0 = blockIdx.y * 128;

    // A staging: row am = tid>>1, k-half ak = (tid&1)*16
    int am = tid >> 1;
    int ak = (tid & 1) << 4;
    const AT* ap = nullptr;
    {
        int r = row0 + am;
        if (r < Mrows) {
            int n = r / nT, tl = r - n * nT;
            ap = A + ((size_t)n * strideT + (size_t)(tbase + tl)) * (size_t)K + ak;
        }
    }
    // B staging: col bn = tid>>1, k-half bk = (tid&1)*16
    int bn = tid >> 1;
    int bk = (tid & 1) << 4;
    const _Float16* bph = Bh + (size_t)(col0 + bn) * K + bk;
    const _Float16* bpl = Bl + (size_t)(col0 + bn) * K + bk;

    f32x4v acc1[4][4] = {};
    f32x4v acc2[4][4] = {};

    float4 fa4[4];
    uint4  ra0, ra1;
    uint4  vbh0, vbh1, vbl0, vbl1;

#define LOAD_TILE(K0) do {                                                  \
    if (ap) {                                                               \
        if (A_F32) {                                                        \
            const float* p_ = (const float*)ap + (K0);                      \
            fa4[0] = *(const float4*)(p_);      fa4[1] = *(const float4*)(p_ + 4);  \
            fa4[2] = *(const float4*)(p_ + 8);  fa4[3] = *(const float4*)(p_ + 12); \
        } else {                                                            \
            const _Float16* p_ = (const _Float16*)ap + (K0);                \
            ra0 = *(const uint4*)(p_);  ra1 = *(const uint4*)(p_ + 8);      \
        }                                                                   \
    } else {                                                                \
        fa4[0] = fa4[1] = fa4[2] = fa4[3] = make_float4(0.f, 0.f, 0.f, 0.f);\
        ra0 = ra1 = make_uint4(0, 0, 0, 0);                                 \
    }                                                                       \
    vbh0 = *(const uint4*)(bph + (K0));  vbh1 = *(const uint4*)(bph + (K0) + 8); \
    vbl0 = *(const uint4*)(bpl + (K0));  vbl1 = *(const uint4*)(bpl + (K0) + 8); \
} while (0)

    LOAD_TILE(0);

    for (int k0 = 0; k0 < K; k0 += 32) {
        // ---- stage to LDS ----
        if (A_F32) {
            _Float16 hv[16];
            const float* fp = (const float*)fa4;
            #pragma unroll
            for (int i = 0; i < 16; ++i) hv[i] = (_Float16)fp[i];
            *(uint4*)&As[am][ak]     = *(const uint4*)&hv[0];
            *(uint4*)&As[am][ak + 8] = *(const uint4*)&hv[8];
        } else {
            *(uint4*)&As[am][ak]     = ra0;
            *(uint4*)&As[am][ak + 8] = ra1;
        }
        *(uint4*)&Bs_h[bn][bk]     = vbh0;
        *(uint4*)&Bs_h[bn][bk + 8] = vbh1;
        *(uint4*)&Bs_l[bn][bk]     = vbl0;
        *(uint4*)&Bs_l[bn][bk + 8] = vbl1;
        __syncthreads();

        // prefetch next tile while MFMAs run
        if (k0 + 32 < K) LOAD_TILE(k0 + 32);

        // ---- fragments + MFMA (2 products) ----
        f16x8 fa[4], fbh[4], fbl[4];
        #pragma unroll
        for (int i = 0; i < 4; ++i)
            fa[i] = *(const f16x8*)&As[wr * 64 + i * 16 + fr][fg * 8];
        #pragma unroll
        for (int j = 0; j < 4; ++j) {
            fbh[j] = *(const f16x8*)&Bs_h[wc * 64 + j * 16 + fr][fg * 8];
            fbl[j] = *(const f16x8*)&Bs_l[wc * 64 + j * 16 + fr][fg * 8];
        }
        #pragma unroll
        for (int i = 0; i < 4; ++i)
            #pragma unroll
            for (int j = 0; j < 4; ++j) {
                acc1[i][j] = __builtin_amdgcn_mfma_f32_16x16x32_f16(fa[i], fbh[j], acc1[i][j], 0, 0, 0);
                acc2[i][j] = __builtin_amdgcn_mfma_f32_16x16x32_f16(fa[i], fbl[j], acc2[i][j], 0, 0, 0);
            }
        __syncthreads();
    }
#undef LOAD_TILE

    // ---- epilogue: combine hi + lo/2048, fp16 store ----
    constexpr float INV = 1.0f / 2048.0f;
    #pragma unroll
    for (int i = 0; i < 4; ++i) {
        #pragma unroll
        for (int q = 0; q < 4; ++q) {
            int rr = row0 + wr * 64 + i * 16 + fg * 4 + q;
            if (rr < Mrows) {
                _Float16* yp = Y + (size_t)rr * Ncols + col0 + wc * 64 + fr;
                #pragma unroll
                for (int j = 0; j < 4; ++j)
                    yp[j * 16] = (_Float16)(acc1[i][j][q] + acc2[i][j][q] * INV);
            }
        }
    }
}

// ---------------- per-row attention logits: alpha_s/alpha_d ----------------

template <int C>
__global__ __launch_bounds__(256) void alpha_kernel(
        const _Float16* __restrict__ h, const float* __restrict__ a_src,
        const float* __restrict__ a_dst, float* __restrict__ as,
        float* __restrict__ ad, int Mrows) {
    constexpr int HC = HEADS * C;
    constexpr int V  = HC / 64;
    int r = blockIdx.x * 4 + (threadIdx.x >> 6);
    if (r >= Mrows) return;
    int lane = threadIdx.x & 63;
    int ch0 = lane * V;
    int head = lane >> 4;
    const _Float16* hp = h + (size_t)r * HC + ch0;
    float s = 0.f, d = 0.f;
    #pragma unroll
    for (int i = 0; i < V; ++i) {
        float v = (float)hp[i];
        s = fmaf(v, a_src[ch0 + i], s);
        d = fmaf(v, a_dst[ch0 + i], d);
    }
    #pragma unroll
    for (int off = 1; off < 16; off <<= 1) {
        s += __shfl_xor(s, off);
        d += __shfl_xor(d, off);
    }
    if ((lane & 15) == 0) {
        as[(size_t)r * HEADS + head] = s;
        ad[(size_t)r * HEADS + head] = d;
    }
}

// ---------------- fused softmax + aggregation ----------------
// No max-pass: exp(v) with v clamped at 80 is mathematically identical to
// exp(v - max) after the normalization. grid (N_NODES, NTOT/NT).

template <int NTOT, int NT, int C, bool RELU, bool TO_OUT, typename OutT>
__global__ __launch_bounds__(HEADS * C) void agg_kernel(
        const _Float16* __restrict__ h, const float* __restrict__ as,
        const float* __restrict__ ad, const int* __restrict__ rp,
        const int* __restrict__ col, const float* __restrict__ bias,
        OutT* __restrict__ out, int t0) {
    constexpr int HC  = HEADS * C;
    constexpr int NW  = HC / 64;       // waves per block (4 or 2)
    constexpr int HPW = HEADS / NW;    // heads per wave in phase A
    constexpr int CHUNK = 64;
    constexpr int WSTR = NT * HEADS + 1;   // odd -> max 2-way bank alias
    constexpr int CG  = HC / 8;        // channel groups
    constexpr int EP  = HC / CG;       // edge-parallel factor = 8

    __shared__ int   s_col[CHUNK];
    __shared__ float s_w[CHUNK][WSTR];
    __shared__ float s_red[NW][NT][HC];
    __shared__ float s_inv[NT][HEADS];

    int n = blockIdx.x;
    int tbase = blockIdx.y * NT;
    int tid = threadIdx.x;
    int wave = tid >> 6, lane = tid & 63;

    int beg = rp[n], end = rp[n + 1];

    float dsum[HPW][NT], adv[HPW][NT];
    #pragma unroll
    for (int hp = 0; hp < HPW; ++hp) {
        int head = wave + hp * NW;
        #pragma unroll
        for (int t = 0; t < NT; ++t) {
            dsum[hp][t] = 0.f;
            adv[hp][t] = ad[((size_t)n * NTOT + tbase + t) * HEADS + head];
        }
    }

    int cg = tid & (CG - 1);
    int eg = tid / CG;
    int hcg = (cg * 8) / C;            // head of this channel group
    float acc[NT][8];
    #pragma unroll
    for (int t = 0; t < NT; ++t)
        #pragma unroll
        for (int j = 0; j < 8; ++j) acc[t][j] = 0.f;

    for (int c0 = beg; c0 < end; c0 += CHUNK) {
        int cnt = min(CHUNK, end - c0);
        if (tid < cnt) s_col[tid] = col[c0 + tid];
        __syncthreads();
        if (lane < cnt) {
            int s = s_col[lane];
            #pragma unroll
            for (int hp = 0; hp < HPW; ++hp) {
                int head = wave + hp * NW;
                #pragma unroll
                for (int t = 0; t < NT; ++t) {
                    float v = as[((size_t)s * NTOT + tbase + t) * HEADS + head] + adv[hp][t];
                    v = v > 0.f ? v : NEG_SLOPE * v;
                    v = fminf(v, 80.f);             // overflow guard
                    float w = __expf(v);
                    dsum[hp][t] += w;
                    s_w[lane][t * HEADS + head] = w;
                }
            }
        }
        __syncthreads();
        for (int e = eg; e < cnt; e += EP) {
            int s = s_col[e];
            const _Float16* hb = h + ((size_t)s * NTOT + tbase) * HC + cg * 8;
            #pragma unroll
            for (int t = 0; t < NT; ++t) {
                float w = s_w[e][t * HEADS + hcg];
                uint4 hv = *(const uint4*)(hb + (size_t)t * HC);
                const _Float16* hx = (const _Float16*)&hv;
                #pragma unroll
                for (int j = 0; j < 8; ++j)
                    acc[t][j] = fmaf((float)hx[j], w, acc[t][j]);
            }
        }
        __syncthreads();
    }

    #pragma unroll
    for (int off = 32; off; off >>= 1)
        #pragma unroll
        for (int hp = 0; hp < HPW; ++hp)
            #pragma unroll
            for (int t = 0; t < NT; ++t)
                dsum[hp][t] += __shfl_xor(dsum[hp][t], off);
    if (lane == 0) {
        #pragma unroll
        for (int hp = 0; hp < HPW; ++hp)
            #pragma unroll
            for (int t = 0; t < NT; ++t)
                s_inv[t][wave + hp * NW] = 1.f / (dsum[hp][t] + 1e-16f);
    }

    #pragma unroll
    for (int off = CG; off < 64; off <<= 1)
        #pragma unroll
        for (int t = 0; t < NT; ++t)
            #pragma unroll
            for (int j = 0; j < 8; ++j)
                acc[t][j] += __shfl_xor(acc[t][j], off);
    if (lane < CG) {
        #pragma unroll
        for (int t = 0; t < NT; ++t) {
            *(float4*)&s_red[wave][t][lane * 8] =
                make_float4(acc[t][0], acc[t][1], acc[t][2], acc[t][3]);
            *(float4*)&s_red[wave][t][lane * 8 + 4] =
                make_float4(acc[t][4], acc[t][5], acc[t][6], acc[t][7]);
        }
    }
    __syncthreads();

    int head_b = tid / C;
    float bv = bias[tid];
    #pragma unroll
    for (int t = 0; t < NT; ++t) {
        float o = 0.f;
        #pragma unroll
        for (int w = 0; w < NW; ++w) o += s_red[w][t][tid];
        o = o * s_inv[t][head_b] + bv;
        if (RELU) o = fmaxf(o, 0.f);
        if (TO_OUT)
            out[((size_t)n * T_STEPS + (size_t)(t0 + tbase + t)) * HC + tid] = (OutT)o;
        else
            out[((size_t)n * NTOT + tbase + t) * HC + tid] = (OutT)o;
    }
}

// ---------------- host ----------------

static inline size_t align256(size_t x) { return (x + 255) & ~(size_t)255; }

static size_t need_ws(int tc) {
    size_t s = 0;
    s += align256(sizeof(int) * (N_NODES + 1));
    s += align256(sizeof(int) * N_NODES);
    s += align256(sizeof(int) * N_EDGES);
    s += 2 * align256(2ull * 128 * 256);                   // w1 hi/lo
    s += 2 * align256(2ull * 256 * 256);                   // w2 hi/lo
    s += 2 * align256(2ull * 256 * 128);                   // w3 hi/lo
    s += 2 * align256(4ull * tc * N_NODES * HEADS);        // as, ad
    s += align256(2ull * tc * N_NODES * 256);              // hbuf (fp16)
    s += align256(2ull * tc * N_NODES * 256);              // buf  (fp16)
    return s;
}

struct Ptrs {
    const float *x, *W1, *av1, *aw1, *b1, *W2, *av2, *aw2, *b2, *W3, *av3, *aw3, *b3;
    float* out;
    int *rp, *col;
    _Float16 *w1h, *w1l, *w2h, *w2l, *w3h, *w3l;
    float *as_b, *ad_b;
    _Float16 *hbuf, *buf;
};

template <int NTOT>
static void run_chunk(const Ptrs& P, int t0, hipStream_t stream) {
    constexpr int NTA  = (NTOT % 3 == 0 && NTOT > 3) ? 3 : NTOT;  // small t-slice: gather WS fits cache
    constexpr int NSPL = NTOT / NTA;
    int Mrows = NTOT * N_NODES;
    dim3 gg1((Mrows + 127) / 128, 2);   // N=256
    dim3 gg3((Mrows + 127) / 128, 1);   // N=128
    dim3 ga(N_NODES, NSPL);
    int ablocks = (Mrows + 3) / 4;

    // layer 1: x -> h (K=128, out 256)
    gemm_mfma<float><<<gg1, 256, 0, stream>>>(P.x, P.w1h, P.w1l, P.hbuf, Mrows, 256, 128, T_STEPS, t0, NTOT);
    alpha_kernel<64><<<ablocks, 256, 0, stream>>>(P.hbuf, P.av1, P.aw1, P.as_b, P.ad_b, Mrows);
    agg_kernel<NTOT, NTA, 64, true, false, _Float16><<<ga, 256, 0, stream>>>(
        P.hbuf, P.as_b, P.ad_b, P.rp, P.col, P.b1, P.buf, t0);

    // layer 2: buf -> h (K=256, out 256)
    gemm_mfma<_Float16><<<gg1, 256, 0, stream>>>(P.buf, P.w2h, P.w2l, P.hbuf, Mrows, 256, 256, NTOT, 0, NTOT);
    alpha_kernel<64><<<ablocks, 256, 0, stream>>>(P.hbuf, P.av2, P.aw2, P.as_b, P.ad_b, Mrows);
    agg_kernel<NTOT, NTA, 64, true, false, _Float16><<<ga, 256, 0, stream>>>(
        P.hbuf, P.as_b, P.ad_b, P.rp, P.col, P.b2, P.buf, t0);

    // layer 3: buf -> h (K=256, out 128) -> d_out
    gemm_mfma<_Float16><<<gg3, 256, 0, stream>>>(P.buf, P.w3h, P.w3l, P.hbuf, Mrows, 128, 256, NTOT, 0, NTOT);
    alpha_kernel<32><<<ablocks, 256, 0, stream>>>(P.hbuf, P.av3, P.aw3, P.as_b, P.ad_b, Mrows);
    agg_kernel<NTOT, NTA, 32, false, true, float><<<ga, 128, 0, stream>>>(
        P.hbuf, P.as_b, P.ad_b, P.rp, P.col, P.b3, P.out, t0);
}

extern "C" void kernel_launch(void* const* d_in, const int* in_sizes, int n_in,
                              void* d_out, int out_size, void* d_ws, size_t ws_size,
                              hipStream_t stream) {
    Ptrs P;
    P.x   = (const float*)d_in[0];
    const int* eidx = (const int*)d_in[1];
    P.W1 = (const float*)d_in[2];  P.av1 = (const float*)d_in[3];
    P.aw1 = (const float*)d_in[4]; P.b1 = (const float*)d_in[5];
    P.W2 = (const float*)d_in[6];  P.av2 = (const float*)d_in[7];
    P.aw2 = (const float*)d_in[8]; P.b2 = (const float*)d_in[9];
    P.W3 = (const float*)d_in[10]; P.av3 = (const float*)d_in[11];
    P.aw3 = (const float*)d_in[12]; P.b3 = (const float*)d_in[13];
    P.out = (float*)d_out;

    const int* src = eidx;
    const int* dst = eidx + N_EDGES;

    int Tc = 1;
    const int cands[6] = {12, 6, 4, 3, 2, 1};
    for (int k = 0; k < 6; ++k) {
        if (need_ws(cands[k]) <= ws_size) { Tc = cands[k]; break; }
    }

    char* p = (char*)d_ws;
    P.rp  = (int*)p; p += align256(sizeof(int) * (N_NODES + 1));
    int* cnt = (int*)p; p += align256(sizeof(int) * N_NODES);
    P.col = (int*)p; p += align256(sizeof(int) * N_EDGES);
    P.w1h = (_Float16*)p; p += align256(2ull * 128 * 256);
    P.w1l = (_Float16*)p; p += align256(2ull * 128 * 256);
    P.w2h = (_Float16*)p; p += align256(2ull * 256 * 256);
    P.w2l = (_Float16*)p; p += align256(2ull * 256 * 256);
    P.w3h = (_Float16*)p; p += align256(2ull * 256 * 128);
    P.w3l = (_Float16*)p; p += align256(2ull * 256 * 128);
    P.as_b = (float*)p; p += align256(4ull * Tc * N_NODES * HEADS);
    P.ad_b = (float*)p; p += align256(4ull * Tc * N_NODES * HEADS);
    P.hbuf = (_Float16*)p; p += align256(2ull * Tc * N_NODES * 256);
    P.buf  = (_Float16*)p;

    // --- build CSR ---
    hipMemsetAsync(cnt, 0, sizeof(int) * N_NODES, stream);
    hist_kernel<<<(N_EDGES + 255) / 256, 256, 0, stream>>>(dst, cnt);
    scan_kernel<<<1, 1024, 0, stream>>>(cnt, P.rp);
    hipMemsetAsync(cnt, 0, sizeof(int) * N_NODES, stream);
    scatter_kernel<<<(N_EDGES + 255) / 256, 256, 0, stream>>>(src, dst, P.rp, cnt, P.col);

    // --- split/transpose weights to fp16 hi/lo (once) ---
    wsplit_kernel<<<(128 * 256 + 255) / 256, 256, 0, stream>>>(P.W1, P.w1h, P.w1l, 128, 256);
    wsplit_kernel<<<(256 * 256 + 255) / 256, 256, 0, stream>>>(P.W2, P.w2h, P.w2l, 256, 256);
    wsplit_kernel<<<(256 * 128 + 255) / 256, 256, 0, stream>>>(P.W3, P.w3h, P.w3l, 256, 128);

    for (int t0 = 0; t0 < T_STEPS; t0 += Tc) {
        switch (Tc) {
            case 12: run_chunk<12>(P, t0, stream); break;
            case 6:  run_chunk<6>(P, t0, stream); break;
            case 4:  run_chunk<4>(P, t0, stream); break;
            case 3:  run_chunk<3>(P, t0, stream); break;
            case 2:  run_chunk<2>(P, t0, stream); break;
            default: run_chunk<1>(P, t0, stream); break;
        }
    }
}

// Round 8
// 1302.717 us; speedup vs baseline: 1.1041x; 1.0880x over previous
//
#include <hip/hip_runtime.h>
#include <cstdint>
#include <cstddef>
#include <type_traits>

#define N_NODES 20000
#define N_EDGES 320000
#define T_STEPS 12
#define HEADS   4
#define NEG_SLOPE 0.2f

typedef unsigned short u16;
typedef unsigned int   u32;

using f16x8  = __attribute__((ext_vector_type(8))) _Float16;
using f32x4v = __attribute__((ext_vector_type(4))) float;

// ---------------- CSR build (dst-sorted), once per call ----------------

__global__ void hist_kernel(const int* __restrict__ dst, int* __restrict__ cnt) {
    int e = blockIdx.x * 256 + threadIdx.x;
    if (e < N_EDGES) atomicAdd(&cnt[dst[e]], 1);
}

__global__ __launch_bounds__(1024) void scan_kernel(const int* __restrict__ cnt,
                                                    int* __restrict__ rp) {
    __shared__ int sd[1024];
    __shared__ int sbase;
    int tid = threadIdx.x;
    if (tid == 0) sbase = 0;
    __syncthreads();
    for (int chunk = 0; chunk < N_NODES; chunk += 1024) {
        int i = chunk + tid;
        int v = (i < N_NODES) ? cnt[i] : 0;
        sd[tid] = v;
        __syncthreads();
        #pragma unroll
        for (int off = 1; off < 1024; off <<= 1) {
            int t = (tid >= off) ? sd[tid - off] : 0;
            __syncthreads();
            sd[tid] += t;
            __syncthreads();
        }
        int incl = sd[tid];
        int base = sbase;
        if (i < N_NODES) rp[i] = base + incl - v;   // exclusive prefix
        __syncthreads();
        if (tid == 1023) sbase = base + incl;
        __syncthreads();
    }
    if (tid == 0) rp[N_NODES] = sbase;              // == N_EDGES
}

__global__ void scatter_kernel(const int* __restrict__ src, const int* __restrict__ dst,
                               const int* __restrict__ rp, int* __restrict__ tmp,
                               int* __restrict__ col) {
    int e = blockIdx.x * 256 + threadIdx.x;
    if (e < N_EDGES) {
        int d = dst[e];
        int pos = rp[d] + atomicAdd(&tmp[d], 1);
        col[pos] = src[e];
    }
}

// ---------------- weight prep: W [K][N] fp32 -> Wt [N][K] fp16 ----------------
// Transposed so the GEMM B-tile staging is a contiguous K-major uint4 read.

__global__ void wconv_kernel(const float* __restrict__ W, _Float16* __restrict__ Wt,
                             int K, int N) {
    int idx = blockIdx.x * 256 + threadIdx.x;
    if (idx >= K * N) return;
    int k = idx / N, n = idx - k * N;
    Wt[(size_t)n * K + k] = (_Float16)W[idx];
}

// ---------------- MFMA GEMM: Y = A @ W, fp16 operands, 128x128 tile ----------
// A fp32 (layer 1: cvt to fp16 in staging) or fp16 (layers 2/3: pure copy
// staging). Single f16 MFMA per (i,j) per K-step; fp32 accumulate.
// Lean on registers/LDS (acc=64 VGPR, 20KB LDS) -> high occupancy hides
// staging latency (round-6 lesson: this loop is latency-bound, not MFMA-bound).
// C/D layout (verified, dtype-independent): col = lane&15, row = (lane>>4)*4+reg.

template <typename AT>
__global__ __launch_bounds__(256) void gemm_mfma(
        const AT* __restrict__ A, const _Float16* __restrict__ B,
        _Float16* __restrict__ Y,
        int Mrows, int Ncols, int K, int strideT, int tbase, int nT) {
    constexpr bool A_F32 = std::is_same<AT, float>::value;
    __shared__ _Float16 As[128][40];    // pad 32->40: 2-way bank alias max
    __shared__ _Float16 Bs[128][40];

    int tid  = threadIdx.x;
    int wave = tid >> 6, lane = tid & 63;
    int wr = wave >> 1, wc = wave & 1;
    int fr = lane & 15, fg = lane >> 4;
    int row0 = blockIdx.x * 128;
    int col0 = blockIdx.y * 128;

    // A staging: row am = tid>>1, k-half ak = (tid&1)*16
    int am = tid >> 1;
    int ak = (tid & 1) << 4;
    const AT* ap = nullptr;
    {
        int r = row0 + am;
        if (r < Mrows) {
            int n = r / nT, tl = r - n * nT;
            ap = A + ((size_t)n * strideT + (size_t)(tbase + tl)) * (size_t)K + ak;
        }
    }
    // B staging: col bn = tid>>1, k-half bk = (tid&1)*16
    int bn = tid >> 1;
    int bk = (tid & 1) << 4;
    const _Float16* bp = B + (size_t)(col0 + bn) * K + bk;

    f32x4v acc[4][4] = {};

    float4 fa4[4];
    uint4  ra0, ra1;
    uint4  vb0, vb1;

#define LOAD_TILE(K0) do {                                                  \
    if (ap) {                                                               \
        if (A_F32) {                                                        \
            const float* p_ = (const float*)ap + (K0);                      \
            fa4[0] = *(const float4*)(p_);      fa4[1] = *(const float4*)(p_ + 4);  \
            fa4[2] = *(const float4*)(p_ + 8);  fa4[3] = *(const float4*)(p_ + 12); \
        } else {                                                            \
            const _Float16* p_ = (const _Float16*)ap + (K0);                \
            ra0 = *(const uint4*)(p_);  ra1 = *(const uint4*)(p_ + 8);      \
        }                                                                   \
    } else {                                                                \
        fa4[0] = fa4[1] = fa4[2] = fa4[3] = make_float4(0.f, 0.f, 0.f, 0.f);\
        ra0 = ra1 = make_uint4(0, 0, 0, 0);                                 \
    }                                                                       \
    vb0 = *(const uint4*)(bp + (K0));  vb1 = *(const uint4*)(bp + (K0) + 8); \
} while (0)

    LOAD_TILE(0);

    for (int k0 = 0; k0 < K; k0 += 32) {
        // ---- stage to LDS ----
        if (A_F32) {
            _Float16 hv[16];
            const float* fp = (const float*)fa4;
            #pragma unroll
            for (int i = 0; i < 16; ++i) hv[i] = (_Float16)fp[i];
            *(uint4*)&As[am][ak]     = *(const uint4*)&hv[0];
            *(uint4*)&As[am][ak + 8] = *(const uint4*)&hv[8];
        } else {
            *(uint4*)&As[am][ak]     = ra0;
            *(uint4*)&As[am][ak + 8] = ra1;
        }
        *(uint4*)&Bs[bn][bk]     = vb0;
        *(uint4*)&Bs[bn][bk + 8] = vb1;
        __syncthreads();

        // prefetch next tile while MFMAs run
        if (k0 + 32 < K) LOAD_TILE(k0 + 32);

        // ---- fragments + MFMA ----
        f16x8 fa[4], fb[4];
        #pragma unroll
        for (int i = 0; i < 4; ++i)
            fa[i] = *(const f16x8*)&As[wr * 64 + i * 16 + fr][fg * 8];
        #pragma unroll
        for (int j = 0; j < 4; ++j)
            fb[j] = *(const f16x8*)&Bs[wc * 64 + j * 16 + fr][fg * 8];
        #pragma unroll
        for (int i = 0; i < 4; ++i)
            #pragma unroll
            for (int j = 0; j < 4; ++j)
                acc[i][j] = __builtin_amdgcn_mfma_f32_16x16x32_f16(fa[i], fb[j], acc[i][j], 0, 0, 0);
        __syncthreads();
    }
#undef LOAD_TILE

    // ---- epilogue: fp16 store ----
    #pragma unroll
    for (int i = 0; i < 4; ++i) {
        #pragma unroll
        for (int q = 0; q < 4; ++q) {
            int rr = row0 + wr * 64 + i * 16 + fg * 4 + q;
            if (rr < Mrows) {
                _Float16* yp = Y + (size_t)rr * Ncols + col0 + wc * 64 + fr;
                #pragma unroll
                for (int j = 0; j < 4; ++j)
                    yp[j * 16] = (_Float16)acc[i][j][q];
            }
        }
    }
}

// ---------------- per-row attention logits: alpha_s/alpha_d ----------------

template <int C>
__global__ __launch_bounds__(256) void alpha_kernel(
        const _Float16* __restrict__ h, const float* __restrict__ a_src,
        const float* __restrict__ a_dst, float* __restrict__ as,
        float* __restrict__ ad, int Mrows) {
    constexpr int HC = HEADS * C;
    constexpr int V  = HC / 64;
    int r = blockIdx.x * 4 + (threadIdx.x >> 6);
    if (r >= Mrows) return;
    int lane = threadIdx.x & 63;
    int ch0 = lane * V;
    int head = lane >> 4;
    const _Float16* hp = h + (size_t)r * HC + ch0;
    float s = 0.f, d = 0.f;
    #pragma unroll
    for (int i = 0; i < V; ++i) {
        float v = (float)hp[i];
        s = fmaf(v, a_src[ch0 + i], s);
        d = fmaf(v, a_dst[ch0 + i], d);
    }
    #pragma unroll
    for (int off = 1; off < 16; off <<= 1) {
        s += __shfl_xor(s, off);
        d += __shfl_xor(d, off);
    }
    if ((lane & 15) == 0) {
        as[(size_t)r * HEADS + head] = s;
        ad[(size_t)r * HEADS + head] = d;
    }
}

// ---------------- fused softmax + aggregation ----------------
// No max-pass: exp(v) with v clamped at 80 is mathematically identical to
// exp(v - max) after the normalization. grid (N_NODES, NTOT/NT).

template <int NTOT, int NT, int C, bool RELU, bool TO_OUT, typename OutT>
__global__ __launch_bounds__(HEADS * C) void agg_kernel(
        const _Float16* __restrict__ h, const float* __restrict__ as,
        const float* __restrict__ ad, const int* __restrict__ rp,
        const int* __restrict__ col, const float* __restrict__ bias,
        OutT* __restrict__ out, int t0) {
    constexpr int HC  = HEADS * C;
    constexpr int NW  = HC / 64;       // waves per block (4 or 2)
    constexpr int HPW = HEADS / NW;    // heads per wave in phase A
    constexpr int CHUNK = 64;
    constexpr int WSTR = NT * HEADS + 1;   // odd -> max 2-way bank alias
    constexpr int CG  = HC / 8;        // channel groups
    constexpr int EP  = HC / CG;       // edge-parallel factor = 8

    __shared__ int   s_col[CHUNK];
    __shared__ float s_w[CHUNK][WSTR];
    __shared__ float s_red[NW][NT][HC];
    __shared__ float s_inv[NT][HEADS];

    int n = blockIdx.x;
    int tbase = blockIdx.y * NT;
    int tid = threadIdx.x;
    int wave = tid >> 6, lane = tid & 63;

    int beg = rp[n], end = rp[n + 1];

    float dsum[HPW][NT], adv[HPW][NT];
    #pragma unroll
    for (int hp = 0; hp < HPW; ++hp) {
        int head = wave + hp * NW;
        #pragma unroll
        for (int t = 0; t < NT; ++t) {
            dsum[hp][t] = 0.f;
            adv[hp][t] = ad[((size_t)n * NTOT + tbase + t) * HEADS + head];
        }
    }

    int cg = tid & (CG - 1);
    int eg = tid / CG;
    int hcg = (cg * 8) / C;            // head of this channel group
    float acc[NT][8];
    #pragma unroll
    for (int t = 0; t < NT; ++t)
        #pragma unroll
        for (int j = 0; j < 8; ++j) acc[t][j] = 0.f;

    for (int c0 = beg; c0 < end; c0 += CHUNK) {
        int cnt = min(CHUNK, end - c0);
        if (tid < cnt) s_col[tid] = col[c0 + tid];
        __syncthreads();
        if (lane < cnt) {
            int s = s_col[lane];
            #pragma unroll
            for (int hp = 0; hp < HPW; ++hp) {
                int head = wave + hp * NW;
                #pragma unroll
                for (int t = 0; t < NT; ++t) {
                    float v = as[((size_t)s * NTOT + tbase + t) * HEADS + head] + adv[hp][t];
                    v = v > 0.f ? v : NEG_SLOPE * v;
                    v = fminf(v, 80.f);             // overflow guard
                    float w = __expf(v);
                    dsum[hp][t] += w;
                    s_w[lane][t * HEADS + head] = w;
                }
            }
        }
        __syncthreads();
        for (int e = eg; e < cnt; e += EP) {
            int s = s_col[e];
            const _Float16* hb = h + ((size_t)s * NTOT + tbase) * HC + cg * 8;
            #pragma unroll
            for (int t = 0; t < NT; ++t) {
                float w = s_w[e][t * HEADS + hcg];
                uint4 hv = *(const uint4*)(hb + (size_t)t * HC);
                const _Float16* hx = (const _Float16*)&hv;
                #pragma unroll
                for (int j = 0; j < 8; ++j)
                    acc[t][j] = fmaf((float)hx[j], w, acc[t][j]);
            }
        }
        __syncthreads();
    }

    #pragma unroll
    for (int off = 32; off; off >>= 1)
        #pragma unroll
        for (int hp = 0; hp < HPW; ++hp)
            #pragma unroll
            for (int t = 0; t < NT; ++t)
                dsum[hp][t] += __shfl_xor(dsum[hp][t], off);
    if (lane == 0) {
        #pragma unroll
        for (int hp = 0; hp < HPW; ++hp)
            #pragma unroll
            for (int t = 0; t < NT; ++t)
                s_inv[t][wave + hp * NW] = 1.f / (dsum[hp][t] + 1e-16f);
    }

    #pragma unroll
    for (int off = CG; off < 64; off <<= 1)
        #pragma unroll
        for (int t = 0; t < NT; ++t)
            #pragma unroll
            for (int j = 0; j < 8; ++j)
                acc[t][j] += __shfl_xor(acc[t][j], off);
    if (lane < CG) {
        #pragma unroll
        for (int t = 0; t < NT; ++t) {
            *(float4*)&s_red[wave][t][lane * 8] =
                make_float4(acc[t][0], acc[t][1], acc[t][2], acc[t][3]);
            *(float4*)&s_red[wave][t][lane * 8 + 4] =
                make_float4(acc[t][4], acc[t][5], acc[t][6], acc[t][7]);
        }
    }
    __syncthreads();

    int head_b = tid / C;
    float bv = bias[tid];
    #pragma unroll
    for (int t = 0; t < NT; ++t) {
        float o = 0.f;
        #pragma unroll
        for (int w = 0; w < NW; ++w) o += s_red[w][t][tid];
        o = o * s_inv[t][head_b] + bv;
        if (RELU) o = fmaxf(o, 0.f);
        if (TO_OUT)
            out[((size_t)n * T_STEPS + (size_t)(t0 + tbase + t)) * HC + tid] = (OutT)o;
        else
            out[((size_t)n * NTOT + tbase + t) * HC + tid] = (OutT)o;
    }
}

// ---------------- host ----------------

static inline size_t align256(size_t x) { return (x + 255) & ~(size_t)255; }

static size_t need_ws(int tc) {
    size_t s = 0;
    s += align256(sizeof(int) * (N_NODES + 1));
    s += align256(sizeof(int) * N_NODES);
    s += align256(sizeof(int) * N_EDGES);
    s += align256(2ull * 128 * 256);                       // w1
    s += align256(2ull * 256 * 256);                       // w2
    s += align256(2ull * 256 * 128);                       // w3
    s += 2 * align256(4ull * tc * N_NODES * HEADS);        // as, ad
    s += align256(2ull * tc * N_NODES * 256);              // hbuf (fp16)
    s += align256(2ull * tc * N_NODES * 256);              // buf  (fp16)
    return s;
}

struct Ptrs {
    const float *x, *W1, *av1, *aw1, *b1, *W2, *av2, *aw2, *b2, *W3, *av3, *aw3, *b3;
    float* out;
    int *rp, *col;
    _Float16 *w1t, *w2t, *w3t;
    float *as_b, *ad_b;
    _Float16 *hbuf, *buf;
};

template <int NTOT>
static void run_chunk(const Ptrs& P, int t0, hipStream_t stream) {
    constexpr int NTA  = (NTOT % 3 == 0 && NTOT > 3) ? 3 : NTOT;  // small t-slice: gather WS fits cache
    constexpr int NSPL = NTOT / NTA;
    int Mrows = NTOT * N_NODES;
    dim3 gg1((Mrows + 127) / 128, 2);   // N=256
    dim3 gg3((Mrows + 127) / 128, 1);   // N=128
    dim3 ga(N_NODES, NSPL);
    int ablocks = (Mrows + 3) / 4;

    // layer 1: x -> h (K=128, out 256)
    gemm_mfma<float><<<gg1, 256, 0, stream>>>(P.x, P.w1t, P.hbuf, Mrows, 256, 128, T_STEPS, t0, NTOT);
    alpha_kernel<64><<<ablocks, 256, 0, stream>>>(P.hbuf, P.av1, P.aw1, P.as_b, P.ad_b, Mrows);
    agg_kernel<NTOT, NTA, 64, true, false, _Float16><<<ga, 256, 0, stream>>>(
        P.hbuf, P.as_b, P.ad_b, P.rp, P.col, P.b1, P.buf, t0);

    // layer 2: buf -> h (K=256, out 256)
    gemm_mfma<_Float16><<<gg1, 256, 0, stream>>>(P.buf, P.w2t, P.hbuf, Mrows, 256, 256, NTOT, 0, NTOT);
    alpha_kernel<64><<<ablocks, 256, 0, stream>>>(P.hbuf, P.av2, P.aw2, P.as_b, P.ad_b, Mrows);
    agg_kernel<NTOT, NTA, 64, true, false, _Float16><<<ga, 256, 0, stream>>>(
        P.hbuf, P.as_b, P.ad_b, P.rp, P.col, P.b2, P.buf, t0);

    // layer 3: buf -> h (K=256, out 128) -> d_out
    gemm_mfma<_Float16><<<gg3, 256, 0, stream>>>(P.buf, P.w3t, P.hbuf, Mrows, 128, 256, NTOT, 0, NTOT);
    alpha_kernel<32><<<ablocks, 256, 0, stream>>>(P.hbuf, P.av3, P.aw3, P.as_b, P.ad_b, Mrows);
    agg_kernel<NTOT, NTA, 32, false, true, float><<<ga, 128, 0, stream>>>(
        P.hbuf, P.as_b, P.ad_b, P.rp, P.col, P.b3, P.out, t0);
}

extern "C" void kernel_launch(void* const* d_in, const int* in_sizes, int n_in,
                              void* d_out, int out_size, void* d_ws, size_t ws_size,
                              hipStream_t stream) {
    Ptrs P;
    P.x   = (const float*)d_in[0];
    const int* eidx = (const int*)d_in[1];
    P.W1 = (const float*)d_in[2];  P.av1 = (const float*)d_in[3];
    P.aw1 = (const float*)d_in[4]; P.b1 = (const float*)d_in[5];
    P.W2 = (const float*)d_in[6];  P.av2 = (const float*)d_in[7];
    P.aw2 = (const float*)d_in[8]; P.b2 = (const float*)d_in[9];
    P.W3 = (const float*)d_in[10]; P.av3 = (const float*)d_in[11];
    P.aw3 = (const float*)d_in[12]; P.b3 = (const float*)d_in[13];
    P.out = (float*)d_out;

    const int* src = eidx;
    const int* dst = eidx + N_EDGES;

    int Tc = 1;
    const int cands[6] = {12, 6, 4, 3, 2, 1};
    for (int k = 0; k < 6; ++k) {
        if (need_ws(cands[k]) <= ws_size) { Tc = cands[k]; break; }
    }

    char* p = (char*)d_ws;
    P.rp  = (int*)p; p += align256(sizeof(int) * (N_NODES + 1));
    int* cnt = (int*)p; p += align256(sizeof(int) * N_NODES);
    P.col = (int*)p; p += align256(sizeof(int) * N_EDGES);
    P.w1t = (_Float16*)p; p += align256(2ull * 128 * 256);
    P.w2t = (_Float16*)p; p += align256(2ull * 256 * 256);
    P.w3t = (_Float16*)p; p += align256(2ull * 256 * 128);
    P.as_b = (float*)p; p += align256(4ull * Tc * N_NODES * HEADS);
    P.ad_b = (float*)p; p += align256(4ull * Tc * N_NODES * HEADS);
    P.hbuf = (_Float16*)p; p += align256(2ull * Tc * N_NODES * 256);
    P.buf  = (_Float16*)p;

    // --- build CSR ---
    hipMemsetAsync(cnt, 0, sizeof(int) * N_NODES, stream);
    hist_kernel<<<(N_EDGES + 255) / 256, 256, 0, stream>>>(dst, cnt);
    scan_kernel<<<1, 1024, 0, stream>>>(cnt, P.rp);
    hipMemsetAsync(cnt, 0, sizeof(int) * N_NODES, stream);
    scatter_kernel<<<(N_EDGES + 255) / 256, 256, 0, stream>>>(src, dst, P.rp, cnt, P.col);

    // --- convert/transpose weights to fp16 (once) ---
    wconv_kernel<<<(128 * 256 + 255) / 256, 256, 0, stream>>>(P.W1, P.w1t, 128, 256);
    wconv_kernel<<<(256 * 256 + 255) / 256, 256, 0, stream>>>(P.W2, P.w2t, 256, 256);
    wconv_kernel<<<(256 * 128 + 255) / 256, 256, 0, stream>>>(P.W3, P.w3t, 256, 128);

    for (int t0 = 0; t0 < T_STEPS; t0 += Tc) {
        switch (Tc) {
            case 12: run_chunk<12>(P, t0, stream); break;
            case 6:  run_chunk<6>(P, t0, stream); break;
            case 4:  run_chunk<4>(P, t0, stream); break;
            case 3:  run_chunk<3>(P, t0, stream); break;
            case 2:  run_chunk<2>(P, t0, stream); break;
            default: run_chunk<1>(P, t0, stream); break;
        }
    }
}